// Round 12
// baseline (448.317 us; speedup 1.0000x reference)
//
#include <hip/hip_runtime.h>

#define HDIM 64
#define EPSBN 1e-5f
#define MNODES 8

typedef unsigned short u16;

__device__ __forceinline__ float bf2f(u16 b) {
    return __uint_as_float(((unsigned)b) << 16);
}
__device__ __forceinline__ u16 f2bf_rne(float f) {
    unsigned u = __float_as_uint(f);
    u += 0x7FFFu + ((u >> 16) & 1u);      // round-to-nearest-even
    return (u16)(u >> 16);
}

// ---------------- degree count ----------------
__global__ void count_edges_k(const int* __restrict__ col, int* __restrict__ cnt, int E) {
    int e = blockIdx.x * blockDim.x + threadIdx.x;
    if (e < E) atomicAdd(&cnt[__builtin_nontemporal_load(&col[e])], 1);
}

// ---------------- exclusive scan of cnt -> offs ----------------
__global__ void scan_partial_k(const int* __restrict__ cnt, int* __restrict__ offs,
                               int* __restrict__ bsum, int n) {
    __shared__ int lds[256];
    int tid = threadIdx.x;
    int base = blockIdx.x * 1024 + tid * 4;
    int v0 = (base + 0 < n) ? cnt[base + 0] : 0;
    int v1 = (base + 1 < n) ? cnt[base + 1] : 0;
    int v2 = (base + 2 < n) ? cnt[base + 2] : 0;
    int v3 = (base + 3 < n) ? cnt[base + 3] : 0;
    int tsum = v0 + v1 + v2 + v3;
    lds[tid] = tsum;
    __syncthreads();
    for (int off = 1; off < 256; off <<= 1) {
        int t = (tid >= off) ? lds[tid - off] : 0;
        __syncthreads();
        lds[tid] += t;
        __syncthreads();
    }
    int excl = lds[tid] - tsum;
    if (tid == 255) bsum[blockIdx.x] = lds[255];
    int run = excl;
    if (base + 0 < n) { offs[base + 0] = run; } run += v0;
    if (base + 1 < n) { offs[base + 1] = run; } run += v1;
    if (base + 2 < n) { offs[base + 2] = run; } run += v2;
    if (base + 3 < n) { offs[base + 3] = run; }
}

// adds block bases (re-scans <=256 block sums in-block), writes cursor + dinv
__global__ void scan_add_k(const int* __restrict__ cnt, int* __restrict__ offs,
                           const int* __restrict__ bsum, int nb,
                           int* __restrict__ cursor, float* __restrict__ dinv,
                           int n, int Etot) {
    __shared__ int lds[256];
    int tid = threadIdx.x;
    int v = (tid < nb) ? bsum[tid] : 0;
    lds[tid] = v;
    __syncthreads();
    for (int off = 1; off < 256; off <<= 1) {
        int t = (tid >= off) ? lds[tid - off] : 0;
        __syncthreads();
        lds[tid] += t;
        __syncthreads();
    }
    int excl = lds[tid] - v;
    __syncthreads();
    lds[tid] = excl;
    __syncthreads();

    int i = blockIdx.x * blockDim.x + tid;
    if (i < n) {
        int o = offs[i] + lds[i >> 10];
        offs[i] = o;
        cursor[i] = o;
        dinv[i] = rsqrtf((float)cnt[i] + 1.0f);   // +1 for self-loop
    }
    if (i == 0) offs[n] = Etot;
}

// ---------------- CSR fill (XCD-ownership, src-only 4 B) + scaled bf16 x pad ----------------
// Streaming col/row/x reads are NON-TEMPORAL so the ~200 KB of partially-filled
// scatter lines stay resident in L2 until full (theory: R11's 107 MB WRITE came
// from LRU eviction by 57 MB of streaming reads, since each XCD class's esrc
// region is only ~0.8 MB and fits in its 4 MB L2).
__global__ void fillpad_k(const int* __restrict__ row, const int* __restrict__ col,
                          int* __restrict__ cursor,
                          int* __restrict__ esrc, int E, int N,
                          const float* __restrict__ x, const float* __restrict__ dinv,
                          u16* __restrict__ xp, int INR, int padTot) {
    int bid = blockIdx.x, tid = threadIdx.x;
    int pidx = bid * 256 + tid;
    if (pidx < padTot) {
        int i = pidx >> 5, k = pidx & 31;
        float xv = (k < INR) ? __builtin_nontemporal_load(&x[i * INR + k]) : 0.f;
        xp[pidx] = f2bf_rne(dinv[i] * xv);          // pre-scaled features
    }
    int xcd = bid & 7;
    int chunk = bid >> 3;
    int e = chunk * 256 + tid;
    if (e >= E) return;
    int c = __builtin_nontemporal_load(&col[e]);
    int owner = (int)(((unsigned long long)c * 8ull) / (unsigned)N);
    if (owner != xcd) return;
    int r = __builtin_nontemporal_load(&row[e]);
    int pos = atomicAdd(&cursor[c], 1);
    esrc[pos] = r;
}

// ---------------- fused conv: 4-node interleaved gather + dense + BN + ReLU ----------------
// Features pre-scaled by dinv (hs = dinv*h, bf16): per-edge work is a pure add;
// conv_i = dinv_i*(hs_i + sum hs_src) @ W. 1 wave/block, 2 groups of 4 nodes;
// 4 independent scalar-load+gather chains in flight per wave.
// SCALEOUT: store dinv_i*y (bf16) for the next layer; else store y (f32) for pool.
template <int KIN, bool SCALEOUT>
__global__ __launch_bounds__(64) void conv_k(
    const u16* __restrict__ hb, const int* __restrict__ offs,
    const int* __restrict__ esrc, const float* __restrict__ dinv,
    const float* __restrict__ W, int KINR,
    const float* __restrict__ bias, const float* __restrict__ g,
    const float* __restrict__ bb, const float* __restrict__ m,
    const float* __restrict__ v, void* __restrict__ hout_, int n) {
    int lane = threadIdx.x;
    float wreg[KIN];
#pragma unroll
    for (int k = 0; k < KIN; k++) wreg[k] = (k < KINR) ? W[k * HDIM + lane] : 0.f;
    const float sc = g[lane] * rsqrtf(v[lane] + EPSBN);
    const float sh = (bias[lane] - m[lane]) * sc + bb[lane];

    __shared__ float agg4[4][KIN];

    const int feat = lane & (KIN - 1);
    auto ldh = [&](int node) -> float {
        return bf2f(hb[(size_t)node * KIN + feat]);
    };

    for (int grp = 0; grp < 2; grp++) {
        int ibase = blockIdx.x * MNODES + grp * 4;
        if (ibase >= n) break;              // wave-uniform
        float acc0 = 0.f, acc1 = 0.f, acc2 = 0.f, acc3 = 0.f;
        int e0 = 0, n0 = 0, e1 = 0, n1 = 0, e2 = 0, n2 = 0, e3 = 0, n3 = 0;
        {
            int i = ibase;
            acc0 = ldh(i); e0 = offs[i]; n0 = offs[i + 1];
            if (ibase + 1 < n) { acc1 = ldh(i + 1); e1 = offs[i + 1]; n1 = offs[i + 2]; }
            if (ibase + 2 < n) { acc2 = ldh(i + 2); e2 = offs[i + 2]; n2 = offs[i + 3]; }
            if (ibase + 3 < n) { acc3 = ldh(i + 3); e3 = offs[i + 3]; n3 = offs[i + 4]; }
        }
        // main loop: 2 edges from each of 4 streams -> 8 independent gathers
        while (e0 + 2 <= n0 && e1 + 2 <= n1 && e2 + 2 <= n2 && e3 + 2 <= n3) {
            int s00 = esrc[e0], s01 = esrc[e0 + 1];
            int s10 = esrc[e1], s11 = esrc[e1 + 1];
            int s20 = esrc[e2], s21 = esrc[e2 + 1];
            int s30 = esrc[e3], s31 = esrc[e3 + 1];
            float h00 = ldh(s00), h01 = ldh(s01);
            float h10 = ldh(s10), h11 = ldh(s11);
            float h20 = ldh(s20), h21 = ldh(s21);
            float h30 = ldh(s30), h31 = ldh(s31);
            acc0 += h00 + h01;
            acc1 += h10 + h11;
            acc2 += h20 + h21;
            acc3 += h30 + h31;
            e0 += 2; e1 += 2; e2 += 2; e3 += 2;
        }
        // drains: 4-wide then scalar, per stream
#define DRAIN(ek, nk, ak)                                                     \
        for (; ek + 4 <= nk; ek += 4) {                                       \
            int a = esrc[ek], b = esrc[ek + 1], c = esrc[ek + 2], d = esrc[ek + 3]; \
            float ha = ldh(a), hb2 = ldh(b), hc = ldh(c), hd = ldh(d);        \
            ak += (ha + hb2) + (hc + hd);                                     \
        }                                                                     \
        for (; ek < nk; ek++) ak += ldh(esrc[ek]);
        DRAIN(e0, n0, acc0)
        DRAIN(e1, n1, acc1)
        DRAIN(e2, n2, acc2)
        DRAIN(e3, n3, acc3)
#undef DRAIN

        __syncthreads();                    // protect agg4 from previous group's readers
        if (lane < KIN) {
            agg4[0][lane] = acc0; agg4[1][lane] = acc1;
            agg4[2][lane] = acc2; agg4[3][lane] = acc3;
        }
        __syncthreads();
        for (int q = 0; q < 4; q++) {
            int i = ibase + q;
            if (i >= n) break;
            float di = dinv[i];
            float dot = 0.f;
            const float4* aggv = (const float4*)agg4[q];
#pragma unroll
            for (int k4 = 0; k4 < KIN / 4; k4++) {
                float4 a = aggv[k4];
                dot = fmaf(a.x, wreg[4 * k4 + 0], dot);
                dot = fmaf(a.y, wreg[4 * k4 + 1], dot);
                dot = fmaf(a.z, wreg[4 * k4 + 2], dot);
                dot = fmaf(a.w, wreg[4 * k4 + 3], dot);
            }
            float y = fmaxf(fmaf(dot * di, sc, sh), 0.f);
            if (SCALEOUT) ((u16*)hout_)[(size_t)i * HDIM + lane] = f2bf_rne(di * y);
            else          ((float*)hout_)[(size_t)i * HDIM + lane] = y;
        }
    }
}

// ---------------- pooling (4 waves per graph) + 2-layer MLP ----------------
__global__ __launch_bounds__(256) void pool_mlp_k(
    const float* __restrict__ h, const int* __restrict__ batch,
    const float* __restrict__ Wc1, const float* __restrict__ bc1,
    const float* __restrict__ Wc2, const float* __restrict__ bc2,
    float* __restrict__ out, int n) {
    int gidx = blockIdx.x;
    int tid = threadIdx.x;
    int lane = tid & 63;
    int wv = tid >> 6;

    int lo = 0, hi = n;
    while (lo < hi) { int mid = (lo + hi) >> 1; if (batch[mid] < gidx) lo = mid + 1; else hi = mid; }
    int start = lo;
    lo = start; hi = n;
    while (lo < hi) { int mid = (lo + hi) >> 1; if (batch[mid] <= gidx) lo = mid + 1; else hi = mid; }
    int end = lo;

    float sum = 0.f, mx = 0.f;   // h >= 0 post-ReLU
    for (int i = start + wv; i < end; i += 4) {
        float val = h[(size_t)i * HDIM + lane];
        sum += val;
        mx = fmaxf(mx, val);
    }
    __shared__ float ssum[4 * HDIM];
    __shared__ float smax[4 * HDIM];
    __shared__ float pooled[2 * HDIM];
    ssum[wv * HDIM + lane] = sum;
    smax[wv * HDIM + lane] = mx;
    __syncthreads();
    if (wv == 0) {
        float sv = ssum[lane] + ssum[64 + lane] + ssum[128 + lane] + ssum[192 + lane];
        float mm = fmaxf(fmaxf(smax[lane], smax[64 + lane]),
                         fmaxf(smax[128 + lane], smax[192 + lane]));
        int cnt = end - start;
        pooled[lane] = sv / fmaxf((float)cnt, 1.f);
        pooled[HDIM + lane] = mm;
    }
    __syncthreads();
    if (wv == 0) {
        float a = bc1[lane];
#pragma unroll
        for (int k = 0; k < 2 * HDIM; k++) a = fmaf(pooled[k], Wc1[k * HDIM + lane], a);
        a = fmaxf(a, 0.f);
#pragma unroll
        for (int c = 0; c < 2; c++) {
            float vv = a * Wc2[lane * 2 + c];
            for (int off = 32; off; off >>= 1) vv += __shfl_down(vv, off);
            if (lane == 0) out[gidx * 2 + c] = vv + bc2[c];
        }
    }
}

extern "C" void kernel_launch(void* const* d_in, const int* in_sizes, int n_in,
                              void* d_out, int out_size, void* d_ws, size_t ws_size,
                              hipStream_t stream) {
    const float* x    = (const float*)d_in[0];
    const int*   erow = (const int*)d_in[1];
    const int*   ecol = (const int*)d_in[2];
    const int*   batch= (const int*)d_in[3];
    const float* W0   = (const float*)d_in[4];
    const float* b0   = (const float*)d_in[5];
    const float* W1   = (const float*)d_in[6];
    const float* b1   = (const float*)d_in[7];
    const float* W2   = (const float*)d_in[8];
    const float* b2   = (const float*)d_in[9];
    const float* bn_g = (const float*)d_in[10];
    const float* bn_b = (const float*)d_in[11];
    const float* bn_m = (const float*)d_in[12];
    const float* bn_v = (const float*)d_in[13];
    const float* Wc1  = (const float*)d_in[14];
    const float* bc1  = (const float*)d_in[15];
    const float* Wc2  = (const float*)d_in[16];
    const float* bc2  = (const float*)d_in[17];
    float* out = (float*)d_out;

    const int N = in_sizes[3];
    const int E = in_sizes[1];
    const int G = out_size / 2;
    const int INR = in_sizes[0] / N;    // 26

    char* ws = (char*)d_ws;
    size_t off = 0;
    auto alloc = [&](size_t bytes) -> void* {
        void* p = ws + off;
        off += (bytes + 255) & ~(size_t)255;
        return p;
    };
    int*   cnt    = (int*)alloc((size_t)N * 4);
    float* dinv   = (float*)alloc((size_t)N * 4);
    int*   offs   = (int*)alloc((size_t)(N + 1) * 4);
    int*   cursor = (int*)alloc((size_t)N * 4);
    int*   bsum   = (int*)alloc(1024);
    int*   esrc   = (int*)alloc((size_t)E * 4 + 256);
    void*  bufA   = alloc((size_t)N * HDIM * 4);   // hs1 (bf16) then h3 (f32)
    void*  bufB   = alloc((size_t)N * HDIM * 4);   // xs (bf16 [N][32]) then hs2 (bf16)
    (void)ws_size;

    // ---- build gcn_norm + CSR transpose ----
    hipMemsetAsync(cnt, 0, (size_t)N * 4, stream);
    count_edges_k<<<(E + 255) / 256, 256, 0, stream>>>(ecol, cnt, E);
    int nb = (N + 1023) / 1024;
    scan_partial_k<<<nb, 256, 0, stream>>>(cnt, offs, bsum, N);
    scan_add_k<<<(N + 255) / 256, 256, 0, stream>>>(cnt, offs, bsum, nb, cursor, dinv, N, E);
    int chunks = (E + 255) / 256;
    fillpad_k<<<chunks * 8, 256, 0, stream>>>(erow, ecol, cursor, esrc, E, N,
                                              x, dinv, (u16*)bufB, INR, N * 32);

    int cgrid = (N + MNODES - 1) / MNODES;
    // ---- layer 0: xs bf16 [N][32] -> hs1 bf16 ----
    conv_k<32, true><<<cgrid, 64, 0, stream>>>((const u16*)bufB, offs, esrc, dinv, W0, INR, b0,
        bn_g + 0, bn_b + 0, bn_m + 0, bn_v + 0, bufA, N);
    // ---- layer 1: hs1 bf16 -> hs2 bf16 ----
    conv_k<64, true><<<cgrid, 64, 0, stream>>>((const u16*)bufA, offs, esrc, dinv, W1, 64, b1,
        bn_g + 64, bn_b + 64, bn_m + 64, bn_v + 64, bufB, N);
    // ---- layer 2: hs2 bf16 -> h3 f32 (unscaled, for pool) ----
    conv_k<64, false><<<cgrid, 64, 0, stream>>>((const u16*)bufB, offs, esrc, dinv, W2, 64, b2,
        bn_g + 128, bn_b + 128, bn_m + 128, bn_v + 128, bufA, N);

    // ---- pool + MLP ----
    pool_mlp_k<<<G, 256, 0, stream>>>((const float*)bufA, batch, Wc1, bc1, Wc2, bc2, out, N);
}